// Round 5
// baseline (166.862 us; speedup 1.0000x reference)
//
#include <hip/hip_runtime.h>
#include <cstdint>

#define L_ 4096
#define NC_ 512
#define CD_ 256
#define H_ 8
#define D_ 128
#define B_ 4
#define SCALE 0.08838834764831845f
#define TAU 3.0e-3f

typedef _Float16 f16x8 __attribute__((ext_vector_type(8)));
typedef _Float16 f16x4 __attribute__((ext_vector_type(4)));
typedef float f32x16 __attribute__((ext_vector_type(16)));
typedef float f32x4 __attribute__((ext_vector_type(4)));

// ---------------------------------------------------------------------------
// Kernel A (verbatim, verified): K16f fp16 fragment-major, K32/V fp32 row-major.
// ---------------------------------------------------------------------------
__global__ __launch_bounds__(256) void kv_pre(
    const float* __restrict__ codes, const float* __restrict__ Wk,
    const float* __restrict__ Wv, _Float16* __restrict__ K16f,
    float* __restrict__ K32, float* __restrict__ V)
{
    __shared__ float clds[8][256];
    const int t = threadIdx.x, h = blockIdx.y, n0 = blockIdx.x * 8;
    {
        const float4* cs = (const float4*)(codes + (size_t)n0 * CD_);
        float4* cd = (float4*)&clds[0][0];
        cd[t] = cs[t]; cd[t + 256] = cs[t + 256];
    }
    __syncthreads();
    const int nl = t >> 5, dq = t & 31, d0 = dq * 4, n = n0 + nl;
    float ak0=0,ak1=0,ak2=0,ak3=0, av0=0,av1=0,av2=0,av3=0;
    const float4* wk4 = (const float4*)Wk;
    const float4* wv4 = (const float4*)Wv;
    for (int c = 0; c < CD_; c += 4) {
        float4 cv = *(const float4*)&clds[nl][c];
        #pragma unroll
        for (int u = 0; u < 4; ++u) {
            float cu = (u==0)?cv.x:(u==1)?cv.y:(u==2)?cv.z:cv.w;
            float4 wk = wk4[((size_t)(c+u)*H_ + h)*32 + dq];
            float4 wv = wv4[((size_t)(c+u)*H_ + h)*32 + dq];
            ak0 = fmaf(cu, wk.x, ak0); ak1 = fmaf(cu, wk.y, ak1);
            ak2 = fmaf(cu, wk.z, ak2); ak3 = fmaf(cu, wk.w, ak3);
            av0 = fmaf(cu, wv.x, av0); av1 = fmaf(cu, wv.y, av1);
            av2 = fmaf(cu, wv.z, av2); av3 = fmaf(cu, wv.w, av3);
        }
    }
    const size_t r32 = ((size_t)(h*NC_ + n))*D_ + d0;
    float4 sk; sk.x=ak0; sk.y=ak1; sk.z=ak2; sk.w=ak3;
    float4 sv; sv.x=av0; sv.y=av1; sv.z=av2; sv.w=av3;
    *(float4*)(K32 + r32) = sk;
    *(float4*)(V   + r32) = sv;
    f16x4 hk; hk[0]=(_Float16)ak0; hk[1]=(_Float16)ak1; hk[2]=(_Float16)ak2; hk[3]=(_Float16)ak3;
    const size_t a16 = ((size_t)((h*16 + (n>>5))*8 + (d0>>4))*64
                        + ((n&31) + ((d0>>3)&1)*32))*8 + (d0&7);
    *(f16x4*)(K16f + a16) = hk;
}

// ---------------------------------------------------------------------------
// Kernel B: q via per-wave DMA'd LDS transpose (double-buffered), K tiles via
// global_load_lds + counted-vmcnt double-buffer (raw s_barrier, never drain
// mid-loop); fp16 MFMA logits + top-2 + exact fp32 repair + fused V gather.
// ---------------------------------------------------------------------------

#define GLD_LDS16(GP, LP)                                                      \
  __builtin_amdgcn_global_load_lds(                                            \
      (const __attribute__((address_space(1))) void*)(GP),                     \
      (__attribute__((address_space(3))) void*)(LP), 16, 0, 0)

#define WAIT_VM(N)  asm volatile("s_waitcnt vmcnt(" #N ")" ::: "memory")
#define WAIT_LGKM   asm volatile("s_waitcnt lgkmcnt(0)" ::: "memory")

__global__ __launch_bounds__(256, 4) void attn_main(
    const float* __restrict__ x, const _Float16* __restrict__ K16f,
    const float* __restrict__ K32, const float* __restrict__ V,
    float* __restrict__ out, float* __restrict__ idxf)
{
    // 32 KB union: [q phase] 4 waves x 2 bufs x 4 KB transpose staging
    //              [K phase] kbuf 2 x 8 KB (offset 0) + qbuf 2 KB (offset 16K)
    __shared__ __align__(16) char smem[32768 + 2048];
    _Float16* kbuf0 = (_Float16*)smem;            // 8 KB  (tile buffer 0)
    _Float16* kbuf1 = (_Float16*)(smem + 8192);   // 8 KB  (tile buffer 1)
    float*    qbuf  = (float*)(smem + 16384);     // 4 x 128 floats (repair)

    const int t = threadIdx.x;
    const int wid = t >> 6, lane = t & 63;
    const int bid = blockIdx.x;
    const int h  = bid & 7;              // head-per-XCD affinity
    const int rr_ = bid >> 3;
    const int lx = rr_ & 31, b = rr_ >> 5;
    const int l0w = lx * 128 + wid * 32;

    const float* xb = x + ((size_t)(b*1024 + h*128)) * L_;
    const int colL = lane & 31;
    const int hi = lane >> 5;
    const int laneN4 = hi * 4;

    // ================= q phase: per-wave DMA transpose =================
    // round r stages x rows [r*32, r*32+32) x cols [l0w, l0w+32) as
    // row-major [32][32] f32 into this wave's buffer (r&1).
    float* qs0 = (float*)(smem + wid * 8192);          // buf 0 (4 KB)
    float* qs1 = (float*)(smem + wid * 8192 + 4096);   // buf 1 (4 KB)

    // per-round DMA: 4 instrs; instr i covers d_local in [i*8, i*8+8)
    // lane -> src row d_local = i*8 + (lane>>3), col group lane&7 (16B)
    #define QSTAGE(RD, QS)                                                     \
      _Pragma("unroll")                                                        \
      for (int i_ = 0; i_ < 4; ++i_) {                                         \
        const float* sp_ = xb + (size_t)((RD)*32 + i_*8 + (lane>>3))*L_        \
                              + l0w + (lane&7)*4;                              \
        GLD_LDS16(sp_, (char*)(QS) + i_*1024);                                 \
      }

    QSTAGE(0, qs0)
    QSTAGE(1, qs1)

    f16x8 qf[8];
    // read round r from QS: covers ds = 2r, 2r+1; d_local = (ds&1)*16 + hi*8 + j
    #define QREAD(RD, QS)                                                      \
      _Pragma("unroll")                                                        \
      for (int p_ = 0; p_ < 2; ++p_) {                                         \
        f16x8 tmp_;                                                            \
        _Pragma("unroll")                                                      \
        for (int j_ = 0; j_ < 8; ++j_)                                         \
          tmp_[j_] = (_Float16)(SCALE * (QS)[(p_*16 + hi*8 + j_)*32 + colL]);  \
        qf[(RD)*2 + p_] = tmp_;                                                \
      }

    WAIT_VM(4);            // round 0 landed
    QREAD(0, qs0)
    WAIT_LGKM;             // round-0 reads consumed before overwriting buf 0
    QSTAGE(2, qs0)
    WAIT_VM(4);            // round 1 landed
    QREAD(1, qs1)
    WAIT_LGKM;
    QSTAGE(3, qs1)
    WAIT_VM(4);            // round 2 landed
    QREAD(2, qs0)
    WAIT_VM(0);            // round 3 landed (drains all x loads)
    QREAD(3, qs1)

    __syncthreads();       // qstage dead; safe to reuse LDS as kbuf

    // ================= K loop: counted-vmcnt double buffer =================
    const _Float16* kh = K16f + ((size_t)h << 16);   // 65536 halfs per head

    // stage tile 0 -> kbuf0 (2 instrs per wave, wid-partitioned 2 KB slices)
    GLD_LDS16(kh + (size_t)(wid*64 + lane)*8,       kbuf0 + (size_t)(wid*64)*8);
    GLD_LDS16(kh + (size_t)(256 + wid*64 + lane)*8, kbuf0 + (size_t)(256 + wid*64)*8);

    float v1 = -INFINITY, v2 = -INFINITY;
    int i1 = 0;

    #pragma unroll 2
    for (int nt = 0; nt < 16; ++nt) {
        _Float16* kcur = (nt & 1) ? kbuf1 : kbuf0;
        _Float16* knxt = (nt & 1) ? kbuf0 : kbuf1;
        if (nt < 15) {   // prefetch tile nt+1 (stays in flight across compute)
            const _Float16* src = kh + (size_t)(nt+1)*4096;
            GLD_LDS16(src + (size_t)(wid*64 + lane)*8,       knxt + (size_t)(wid*64)*8);
            GLD_LDS16(src + (size_t)(256 + wid*64 + lane)*8, knxt + (size_t)(256 + wid*64)*8);
            WAIT_VM(2);                       // tile nt landed (nt+1 still in flight)
        } else {
            WAIT_VM(0);                       // last tile landed
        }
        __builtin_amdgcn_s_barrier();         // B1: cur ready for all waves

        f32x16 acc;
        #pragma unroll
        for (int r = 0; r < 16; ++r) acc[r] = 0.f;
        #pragma unroll
        for (int ds = 0; ds < 8; ++ds) {
            f16x8 kf = *(const f16x8*)(kcur + (size_t)(ds*64 + lane)*8);
            acc = __builtin_amdgcn_mfma_f32_32x32x16_f16(kf, qf[ds], acc, 0, 0, 0);
        }
        const int nb = nt*32 + laneN4;
        #pragma unroll
        for (int r = 0; r < 16; ++r) {
            const int n = nb + (r & 3) + ((r >> 2) << 3);
            float v = acc[r];
            bool g = v > v1;
            v2 = fmaxf(v2, fminf(v1, v));
            v1 = fmaxf(v1, v);
            i1 = g ? n : i1;
        }
        __builtin_amdgcn_s_barrier();         // B2: readers done before overwrite
    }

    // ---- merge lane^32 halves (n-rows split by +4*hi)
    float o1 = __shfl_xor(v1, 32), o2 = __shfl_xor(v2, 32);
    int oi = __shfl_xor(i1, 32);
    bool sw = (o1 > v1) || (o1 == v1 && oi < i1);
    const float V1 = sw ? o1 : v1;
    int idx = sw ? oi : i1;
    const float V2 = fmaxf(fminf(v1, o1), fmaxf(v2, o2));

    // ---- exact fp32 full repair for near-ties (one ballot bit per l-row)
    unsigned long long mf = __ballot(V1 - V2 < TAU) & 0xffffffffull;
    float* qb = qbuf + wid * 128;
    while (mf) {
        int src = (int)__builtin_ctzll(mf); mf &= mf - 1;
        int rl = l0w + src;
        qb[lane]      = SCALE * xb[(size_t)lane*L_ + rl];
        qb[lane + 64] = SCALE * xb[(size_t)(lane+64)*L_ + rl];
        __builtin_amdgcn_wave_barrier();
        WAIT_LGKM;
        float accs[8];
        #pragma unroll
        for (int u = 0; u < 8; ++u) accs[u] = 0.f;
        const float* kr = K32 + ((size_t)(h*NC_ + lane))*D_;
        for (int d4 = 0; d4 < 32; ++d4) {
            float qd0 = qb[d4*4+0], qd1 = qb[d4*4+1], qd2 = qb[d4*4+2], qd3 = qb[d4*4+3];
            #pragma unroll
            for (int u = 0; u < 8; ++u) {
                f32x4 kk = *(const f32x4*)(kr + (size_t)u*64*D_ + d4*4);
                accs[u] = fmaf(qd0, kk[0], accs[u]);
                accs[u] = fmaf(qd1, kk[1], accs[u]);
                accs[u] = fmaf(qd2, kk[2], accs[u]);
                accs[u] = fmaf(qd3, kk[3], accs[u]);
            }
        }
        float bv = -INFINITY; int bn = 0;
        #pragma unroll
        for (int u = 0; u < 8; ++u) {
            if (accs[u] > bv) { bv = accs[u]; bn = lane + (u << 6); }
        }
        #pragma unroll
        for (int m = 1; m < 64; m <<= 1) {
            float ov = __shfl_xor(bv, m);
            int on = __shfl_xor(bn, m);
            if (ov > bv || (ov == bv && on < bn)) { bv = ov; bn = on; }
        }
        if (lane == src) idx = bn;
        __builtin_amdgcn_wave_barrier();
    }
    idx = __shfl(idx, colL);   // broadcast repaired idx to the hi-half lane

    // ---- outputs: idx (as float, lanes 0-31) + fused V gather (d split by hi)
    const int myl = l0w + colL;
    if (!hi) idxf[((size_t)(b*H_ + h))*L_ + myl] = (float)idx;
    const f32x4* vrow = (const f32x4*)(V + ((size_t)(h*NC_ + idx))*D_);
    float* ob = out + ((size_t)(b*1024 + h*128 + hi*64))*L_ + myl;
    #pragma unroll
    for (int p = 0; p < 16; ++p) {
        f32x4 vv = vrow[hi*16 + p];
        ob[(size_t)(p*4+0)*L_] = vv[0];
        ob[(size_t)(p*4+1)*L_] = vv[1];
        ob[(size_t)(p*4+2)*L_] = vv[2];
        ob[(size_t)(p*4+3)*L_] = vv[3];
    }
}

extern "C" void kernel_launch(void* const* d_in, const int* in_sizes, int n_in,
                              void* d_out, int out_size, void* d_ws, size_t ws_size,
                              hipStream_t stream)
{
    const float* x     = (const float*)d_in[0];
    const float* codes = (const float*)d_in[1];
    const float* Wk    = (const float*)d_in[2];
    const float* Wv    = (const float*)d_in[3];

    float* out  = (float*)d_out;
    float* idxf = out + (size_t)B_ * H_ * D_ * L_;

    _Float16* K16f = (_Float16*)d_ws;                        // 1 MB
    float*    K32  = (float*)((char*)d_ws + (1u << 20));     // 2 MB
    float*    Vf   = (float*)((char*)d_ws + (3u << 20));     // 2 MB

    kv_pre<<<dim3(64, 8), 256, 0, stream>>>(codes, Wk, Wv, K16f, K32, Vf);
    attn_main<<<dim3(1024), 256, 0, stream>>>(x, K16f, K32, Vf, out, idxf);
}